// Round 6
// baseline (67.940 us; speedup 1.0000x reference)
//
#include <hip/hip_runtime.h>
#include <hip/hip_bf16.h>
#include <math.h>

#define NB 512
#define NQ 30
#define ND 512
#define NE 128
#define NK 21
#define VOCAB 50000

typedef __attribute__((ext_vector_type(4))) float f32x4;
typedef __attribute__((ext_vector_type(8))) short short8;

// normalized vocab table, bf16 (12.8 MB). Fully rewritten every launch (idempotent).
__device__ unsigned short g_norm[(size_t)VOCAB * NE];
// per-(b,dquarter) partials for ALL 21 kernels incl. exact-match count at k=20.
// Plain stores only, every element rewritten every launch. No atomics, no zeroing.
__device__ float g_Sp[(size_t)NB * 4 * NQ * NK];

__device__ __forceinline__ unsigned short f2bf(float f) {
  unsigned int x = __builtin_bit_cast(unsigned int, f);
  x = (x + 0x7fffu + ((x >> 16) & 1u)) >> 16;   // RNE
  return (unsigned short)x;
}

// ---------------- kernel 1: normalize vocab to bf16 ----------------
__global__ __launch_bounds__(256) void norm_kernel(const float* __restrict__ emb) {
  const int t = threadIdx.x;
  const int row = blockIdx.x * 8 + (t >> 5);
  const int j = t & 31;
  const float* src = emb + (size_t)row * NE;
  float4 v = *(const float4*)(src + j * 4);
  float ssq = v.x * v.x + v.y * v.y + v.z * v.z + v.w * v.w;
  ssq += __shfl_xor(ssq, 1);
  ssq += __shfl_xor(ssq, 2);
  ssq += __shfl_xor(ssq, 4);
  ssq += __shfl_xor(ssq, 8);
  ssq += __shfl_xor(ssq, 16);
  const float sc = 1.0f / fmaxf(sqrtf(ssq), 1e-12f);
  ushort4 o;
  o.x = f2bf(v.x * sc); o.y = f2bf(v.y * sc);
  o.z = f2bf(v.z * sc); o.w = f2bf(v.w * sc);
  *(ushort4*)(g_norm + (size_t)row * NE + j * 4) = o;
}

// ---------------- kernel 2: partial KNRM (128 doc rows x 32 q per block) ----------------
// 512 threads = 8 waves; wave w: qt=w&1 (16 q), dg=w>>1 (32 d rows).
// LDS: dtile 32KB + qtile 8KB = 40960B -> 4 blocks/CU.
__global__ __launch_bounds__(512, 8) void knrm_part(
    const int* __restrict__ query, const int* __restrict__ doc)
{
  extern __shared__ unsigned char smem_raw[];
  unsigned short* dtile = (unsigned short*)smem_raw;   // [128][128] bf16, 16B-slot swizzled
  unsigned short* qtile = dtile + 128 * NE;            // [32][128]  bf16, swizzled

  const int t = threadIdx.x;
  // XCD swizzle: XCD x gets b in [x*64, (x+1)*64) contiguous.
  const unsigned bid = blockIdx.x;
  const unsigned swz = (bid & 7) * 256 + (bid >> 3);
  const int b  = swz >> 2;
  const int dq = swz & 3;
  const int d0 = dq * 128;

  const int srow = t >> 4, slot = t & 15;
  // ---- stage 128 doc rows: 4 rounds x (32 rows x 16 lanes x 16B) ----
  short8 pay[4];
#pragma unroll
  for (int rnd = 0; rnd < 4; ++rnd) {
    const int r = rnd * 32 + srow;
    const int id = doc[b * ND + d0 + r];
    pay[rnd] = *(const short8*)(g_norm + (size_t)id * NE + slot * 8);
  }
#pragma unroll
  for (int rnd = 0; rnd < 4; ++rnd) {
    const int r = rnd * 32 + srow;
    *(short8*)(dtile + r * NE + ((slot ^ (r & 7)) * 8)) = pay[rnd];
  }
  // ---- stage 32 query rows (30 real + 2 zero), all 512 threads ----
  {
    short8 qv = (short8){0, 0, 0, 0, 0, 0, 0, 0};
    if (srow < NQ)
      qv = *(const short8*)(g_norm + (size_t)query[b * NQ + srow] * NE + slot * 8);
    *(short8*)(qtile + srow * NE + ((slot ^ (srow & 7)) * 8)) = qv;
  }
  __syncthreads();

  const int wave = t >> 6, lane = t & 63;
  const int lrow = lane & 15, lgrp = lane >> 4;
  const int qt = wave & 1, dg = wave >> 1;

  // ---- mm^T tile: C[d][q]; A and B from swizzled LDS ----
  f32x4 acc[2];
  acc[0] = (f32x4){0.f, 0.f, 0.f, 0.f};
  acc[1] = (f32x4){0.f, 0.f, 0.f, 0.f};
  const int qrow = qt * 16 + lrow;
#pragma unroll
  for (int ks = 0; ks < 4; ++ks) {
    const int qs = (ks * 4 + lgrp) ^ (qrow & 7);
    short8 bq = *(const short8*)(qtile + qrow * NE + qs * 8);
#pragma unroll
    for (int dt = 0; dt < 2; ++dt) {
      const int R = dg * 32 + dt * 16 + lrow;
      const int as = (ks * 4 + lgrp) ^ (R & 7);
      short8 a = *(const short8*)(dtile + R * NE + as * 8);
      acc[dt] = __builtin_amdgcn_mfma_f32_16x16x32_bf16(a, bq, acc[dt], 0, 0, 0);
    }
  }
  __syncthreads();   // LDS tiles consumed -> reuse dtile region

  float* Sw  = (float*)dtile;        // [8 waves][16 lrow][20 k] = 10240 B
  float* Sex = Sw + 8 * 16 * 20;     // [32] exact-match counts (block-local)
  if (t < 32) Sex[t] = 0.0f;
  __syncthreads();

  // ---- exact-match kernel (mu=1, sigma=0.001): integer ID equality ----
  // Block-local LDS atomics only (all +1.0: exact integer sums, order-free).
  if (t < 128) {
    const int did = doc[b * ND + d0 + t];
    const int* qp = query + b * NQ;   // uniform -> scalar loads
#pragma unroll
    for (int q = 0; q < NQ; ++q)
      if (did == qp[q]) atomicAdd(&Sex[q], 1.0f);
  }

  // ---- kernel pooling: s_k = 2^{Cc*mu^2} * sum_d exp2(m*(Cc*m + bk)) ----
  const float Cc = -72.13475204444817f;  // -1/(2*0.1^2*ln2)
  float m[8];
#pragma unroll
  for (int dt = 0; dt < 2; ++dt)
#pragma unroll
    for (int r = 0; r < 4; ++r) m[dt * 4 + r] = acc[dt][r];

#pragma unroll 2
  for (int k = 0; k < 20; ++k) {
    const float mu  = fmaf(0.1f, (float)k, -0.95f);
    const float bk  = -2.0f * Cc * mu;
    const float sck = __builtin_amdgcn_exp2f(Cc * mu * mu);
    float s0 = 0.f, s1 = 0.f;
#pragma unroll
    for (int i = 0; i < 8; i += 2) {
      s0 += __builtin_amdgcn_exp2f(m[i    ] * fmaf(Cc, m[i    ], bk));
      s1 += __builtin_amdgcn_exp2f(m[i + 1] * fmaf(Cc, m[i + 1], bk));
    }
    float s = s0 + s1;
    s += __shfl_xor(s, 16);
    s += __shfl_xor(s, 32);
    if (lgrp == 0) Sw[(wave * 16 + lrow) * 20 + k] = s * sck;
  }
  __syncthreads();

  // ---- block reduce -> plain store of ALL 21 kernels for this (b,dq) ----
  for (int i = t; i < NQ * NK; i += 512) {
    const int q = i / NK, k = i % NK;
    float v;
    if (k < 20) {
      const int w0 = q >> 4;
      v = 0.f;
#pragma unroll
      for (int g = 0; g < 4; ++g) v += Sw[((g * 2 + w0) * 16 + (q & 15)) * 20 + k];
    } else {
      v = Sex[q];
    }
    g_Sp[(((size_t)b * 4 + dq) * NQ + q) * NK + k] = v;
  }
}

// ---------------- kernel 3: log1p + MLP ----------------
__global__ __launch_bounds__(64) void knrm_finish(
    const float* __restrict__ w1, const float* __restrict__ b1,
    const float* __restrict__ w2, const float* __restrict__ b2,
    const float* __restrict__ w3, const float* __restrict__ b3,
    float* __restrict__ out)
{
  __shared__ float km[NK], h1[10], h2[5];
  const int b = blockIdx.x, t = threadIdx.x;
  if (t < NK) {
    float s = 0.f;
    for (int q = 0; q < NQ; ++q) {
      float v = 0.f;
#pragma unroll
      for (int g = 0; g < 4; ++g)
        v += g_Sp[(((size_t)b * 4 + g) * NQ + q) * NK + t];
      s += log1pf(v);
    }
    km[t] = s;
  }
  __syncthreads();
  if (t < 10) {
    float a = b1[t];
#pragma unroll 1
    for (int k = 0; k < NK; ++k) a = fmaf(km[k], w1[k * 10 + t], a);
    h1[t] = fmaxf(a, 0.f);
  }
  __syncthreads();
  if (t < 5) {
    float a = b2[t];
#pragma unroll 1
    for (int k = 0; k < 10; ++k) a = fmaf(h1[k], w2[k * 5 + t], a);
    h2[t] = fmaxf(a, 0.f);
  }
  __syncthreads();
  if (t == 0) {
    float a = b3[0];
#pragma unroll 1
    for (int k = 0; k < 5; ++k) a = fmaf(h2[k], w3[k], a);
    out[b] = a;
  }
}

extern "C" void kernel_launch(void* const* d_in, const int* in_sizes, int n_in,
                              void* d_out, int out_size, void* d_ws, size_t ws_size,
                              hipStream_t stream) {
  const int*   query = (const int*)d_in[0];
  const int*   doc   = (const int*)d_in[1];
  const float* emb   = (const float*)d_in[2];
  const float* w1    = (const float*)d_in[3];
  const float* b1    = (const float*)d_in[4];
  const float* w2    = (const float*)d_in[5];
  const float* b2    = (const float*)d_in[6];
  const float* w3    = (const float*)d_in[7];
  const float* b3    = (const float*)d_in[8];
  float* out = (float*)d_out;

  const size_t sh = (size_t)128 * NE * 2    // dtile 32768
                  + (size_t)32 * NE * 2;    // qtile  8192  -> 40960 total
  hipFuncSetAttribute((const void*)knrm_part,
                      hipFuncAttributeMaxDynamicSharedMemorySize, (int)sh);

  norm_kernel<<<dim3(VOCAB / 8), dim3(256), 0, stream>>>(emb);
  knrm_part<<<dim3(NB * 4), dim3(512), sh, stream>>>(query, doc);
  knrm_finish<<<dim3(NB), dim3(64), 0, stream>>>(w1, b1, w2, b2, w3, b3, out);
}

// Round 7
// 66.608 us; speedup vs baseline: 1.0200x; 1.0200x over previous
//
#include <hip/hip_runtime.h>
#include <hip/hip_bf16.h>
#include <math.h>

#define NB 512
#define NQ 30
#define ND 512
#define NE 128
#define NK 21
#define VOCAB 50000

typedef __attribute__((ext_vector_type(4))) float f32x4;
typedef __attribute__((ext_vector_type(8))) short short8;

#define AS1C(p) ((const __attribute__((address_space(1))) unsigned int*)(p))
#define AS3C(p) ((__attribute__((address_space(3))) unsigned int*)(p))

// normalized vocab table, bf16 (12.8 MB). Fully rewritten every launch (idempotent).
__device__ unsigned short g_norm[(size_t)VOCAB * NE];
// per-(b,dquarter) partials for ALL 21 kernels incl. exact-match count at k=20.
// Plain stores only, every element rewritten every launch. No atomics, no zeroing.
__device__ float g_Sp[(size_t)NB * 4 * NQ * NK];
// 256B of zeros for padding q-rows 30,31. Never written -> stays zero.
__device__ unsigned short g_zero[NE];

__device__ __forceinline__ unsigned short f2bf(float f) {
  unsigned int x = __builtin_bit_cast(unsigned int, f);
  x = (x + 0x7fffu + ((x >> 16) & 1u)) >> 16;   // RNE
  return (unsigned short)x;
}

// ---------------- kernel 1: normalize vocab to bf16 ----------------
__global__ __launch_bounds__(256) void norm_kernel(const float* __restrict__ emb) {
  const int t = threadIdx.x;
  const int row = blockIdx.x * 8 + (t >> 5);
  const int j = t & 31;
  const float* src = emb + (size_t)row * NE;
  float4 v = *(const float4*)(src + j * 4);
  float ssq = v.x * v.x + v.y * v.y + v.z * v.z + v.w * v.w;
  ssq += __shfl_xor(ssq, 1);
  ssq += __shfl_xor(ssq, 2);
  ssq += __shfl_xor(ssq, 4);
  ssq += __shfl_xor(ssq, 8);
  ssq += __shfl_xor(ssq, 16);
  const float sc = 1.0f / fmaxf(sqrtf(ssq), 1e-12f);
  ushort4 o;
  o.x = f2bf(v.x * sc); o.y = f2bf(v.y * sc);
  o.z = f2bf(v.z * sc); o.w = f2bf(v.w * sc);
  *(ushort4*)(g_norm + (size_t)row * NE + j * 4) = o;
}

// ---------------- kernel 2: partial KNRM (128 doc rows x 32 q per block) ----------------
// 512 threads = 8 waves; wave w: qt=w&1 (16 q), dg=w>>1 (32 d rows).
// LDS: dtile 32KB + qtile 8KB = 40960B -> 4 blocks/CU.
// Staging via global_load_lds: swizzle applied to the GLOBAL source slot,
// LDS dest is linear (wave-uniform base + lane*16), read side swizzled as before.
__global__ __launch_bounds__(512, 8) void knrm_part(
    const int* __restrict__ query, const int* __restrict__ doc)
{
  extern __shared__ unsigned char smem_raw[];
  unsigned short* dtile = (unsigned short*)smem_raw;   // [128][128] bf16, slot-swizzled
  unsigned short* qtile = dtile + 128 * NE;            // [32][128]  bf16, slot-swizzled

  const int t = threadIdx.x;
  // XCD swizzle: XCD x gets b in [x*64, (x+1)*64) contiguous. 2048 % 8 == 0 -> bijective.
  const unsigned bid = blockIdx.x;
  const unsigned swz = (bid & 7) * 256 + (bid >> 3);
  const int b  = swz >> 2;
  const int dq = swz & 3;
  const int d0 = dq * 128;

  const int wave = t >> 6, lane = t & 63;
  const int srow4 = lane >> 4, slot = lane & 15;

  // ---- stage 128 doc rows: 4 x global_load_lds(16B), zero VGPR payload ----
#pragma unroll
  for (int rnd = 0; rnd < 4; ++rnd) {
    const int r = rnd * 32 + wave * 4 + srow4;
    const int id = doc[b * ND + d0 + r];
    const unsigned short* src = g_norm + (size_t)id * NE + ((slot ^ (r & 7)) * 8);
    unsigned short* ldst = dtile + (rnd * 32 + wave * 4) * NE;  // wave-uniform
    __builtin_amdgcn_global_load_lds(AS1C(src), AS3C(ldst), 16, 0, 0);
  }
  // ---- stage 32 query rows (30 real + 2 zero), one round ----
  {
    const int qr = wave * 4 + srow4;
    const unsigned short* srcrow =
        (qr < NQ) ? (g_norm + (size_t)query[b * NQ + qr] * NE) : g_zero;
    const unsigned short* src = srcrow + ((slot ^ (qr & 7)) * 8);
    unsigned short* ldst = qtile + (wave * 4) * NE;             // wave-uniform
    __builtin_amdgcn_global_load_lds(AS1C(src), AS3C(ldst), 16, 0, 0);
  }
  __syncthreads();   // drains vmcnt -> tiles complete

  const int lrow = lane & 15, lgrp = lane >> 4;
  const int qt = wave & 1, dg = wave >> 1;

  // ---- mm^T tile: C[d][q]; A and B from swizzled LDS ----
  f32x4 acc[2];
  acc[0] = (f32x4){0.f, 0.f, 0.f, 0.f};
  acc[1] = (f32x4){0.f, 0.f, 0.f, 0.f};
  const int qrow = qt * 16 + lrow;
#pragma unroll
  for (int ks = 0; ks < 4; ++ks) {
    const int qs = (ks * 4 + lgrp) ^ (qrow & 7);
    short8 bq = *(const short8*)(qtile + qrow * NE + qs * 8);
#pragma unroll
    for (int dt = 0; dt < 2; ++dt) {
      const int R = dg * 32 + dt * 16 + lrow;
      const int as = (ks * 4 + lgrp) ^ (R & 7);
      short8 a = *(const short8*)(dtile + R * NE + as * 8);
      acc[dt] = __builtin_amdgcn_mfma_f32_16x16x32_bf16(a, bq, acc[dt], 0, 0, 0);
    }
  }
  __syncthreads();   // LDS tiles consumed -> reuse dtile region

  float* Sw  = (float*)dtile;        // [8 waves][16 lrow][20 k] = 10240 B
  float* Sex = Sw + 8 * 16 * 20;     // [32] exact-match counts (block-local)
  if (t < 32) Sex[t] = 0.0f;
  __syncthreads();

  // ---- exact-match kernel (mu=1, sigma=0.001): integer ID equality ----
  // Block-local LDS atomics only (all +1.0: exact integer sums, order-free).
  if (t < 128) {
    const int did = doc[b * ND + d0 + t];
    const int* qp = query + b * NQ;   // uniform -> scalar loads
#pragma unroll
    for (int q = 0; q < NQ; ++q)
      if (did == qp[q]) atomicAdd(&Sex[q], 1.0f);
  }

  // ---- kernel pooling: s_k = sum_d exp2(Cc*(m-mu)^2), arg = fma(m, fma(Cc,m,bk), gk) ----
  const float Cc = -72.13475204444817f;  // -1/(2*0.1^2*ln2)
  float m[8];
#pragma unroll
  for (int dt = 0; dt < 2; ++dt)
#pragma unroll
    for (int r = 0; r < 4; ++r) m[dt * 4 + r] = acc[dt][r];

#pragma unroll 2
  for (int k = 0; k < 20; ++k) {
    const float mu = fmaf(0.1f, (float)k, -0.95f);
    const float bk = -2.0f * Cc * mu;
    const float gk = Cc * mu * mu;
    float s0 = 0.f, s1 = 0.f;
#pragma unroll
    for (int i = 0; i < 8; i += 2) {
      s0 += __builtin_amdgcn_exp2f(fmaf(m[i    ], fmaf(Cc, m[i    ], bk), gk));
      s1 += __builtin_amdgcn_exp2f(fmaf(m[i + 1], fmaf(Cc, m[i + 1], bk), gk));
    }
    float s = s0 + s1;
    s += __shfl_xor(s, 16);
    s += __shfl_xor(s, 32);
    if (lgrp == 0) Sw[(wave * 16 + lrow) * 20 + k] = s;
  }
  __syncthreads();

  // ---- block reduce -> plain store of ALL 21 kernels for this (b,dq) ----
  for (int i = t; i < NQ * NK; i += 512) {
    const int q = i / NK, k = i % NK;
    float v;
    if (k < 20) {
      const int w0 = q >> 4;
      v = 0.f;
#pragma unroll
      for (int g = 0; g < 4; ++g) v += Sw[((g * 2 + w0) * 16 + (q & 15)) * 20 + k];
    } else {
      v = Sex[q];
    }
    g_Sp[(((size_t)b * 4 + dq) * NQ + q) * NK + k] = v;
  }
}

// ---------------- kernel 3: log1p + MLP ----------------
__global__ __launch_bounds__(64) void knrm_finish(
    const float* __restrict__ w1, const float* __restrict__ b1,
    const float* __restrict__ w2, const float* __restrict__ b2,
    const float* __restrict__ w3, const float* __restrict__ b3,
    float* __restrict__ out)
{
  __shared__ float km[NK], h1[10], h2[5];
  const int b = blockIdx.x, t = threadIdx.x;
  if (t < NK) {
    float s = 0.f;
    for (int q = 0; q < NQ; ++q) {
      float v = 0.f;
#pragma unroll
      for (int g = 0; g < 4; ++g)
        v += g_Sp[(((size_t)b * 4 + g) * NQ + q) * NK + t];
      s += log1pf(v);
    }
    km[t] = s;
  }
  __syncthreads();
  if (t < 10) {
    float a = b1[t];
#pragma unroll 1
    for (int k = 0; k < NK; ++k) a = fmaf(km[k], w1[k * 10 + t], a);
    h1[t] = fmaxf(a, 0.f);
  }
  __syncthreads();
  if (t < 5) {
    float a = b2[t];
#pragma unroll 1
    for (int k = 0; k < 10; ++k) a = fmaf(h1[k], w2[k * 5 + t], a);
    h2[t] = fmaxf(a, 0.f);
  }
  __syncthreads();
  if (t == 0) {
    float a = b3[0];
#pragma unroll 1
    for (int k = 0; k < 5; ++k) a = fmaf(h2[k], w3[k], a);
    out[b] = a;
  }
}

extern "C" void kernel_launch(void* const* d_in, const int* in_sizes, int n_in,
                              void* d_out, int out_size, void* d_ws, size_t ws_size,
                              hipStream_t stream) {
  const int*   query = (const int*)d_in[0];
  const int*   doc   = (const int*)d_in[1];
  const float* emb   = (const float*)d_in[2];
  const float* w1    = (const float*)d_in[3];
  const float* b1    = (const float*)d_in[4];
  const float* w2    = (const float*)d_in[5];
  const float* b2    = (const float*)d_in[6];
  const float* w3    = (const float*)d_in[7];
  const float* b3    = (const float*)d_in[8];
  float* out = (float*)d_out;

  const size_t sh = (size_t)128 * NE * 2    // dtile 32768
                  + (size_t)32 * NE * 2;    // qtile  8192  -> 40960 total
  hipFuncSetAttribute((const void*)knrm_part,
                      hipFuncAttributeMaxDynamicSharedMemorySize, (int)sh);

  norm_kernel<<<dim3(VOCAB / 8), dim3(256), 0, stream>>>(emb);
  knrm_part<<<dim3(NB * 4), dim3(512), sh, stream>>>(query, doc);
  knrm_finish<<<dim3(NB), dim3(64), 0, stream>>>(w1, b1, w2, b2, w3, b3, out);
}